// Round 1
// baseline (230.284 us; speedup 1.0000x reference)
//
#include <hip/hip_runtime.h>
#include <math.h>

namespace {

constexpr int B = 64;
constexpr int T = 4096;
constexpr int H = 1024;
constexpr float SCALE = 0.03125f;  // 1/sqrt(1024)
constexpr int WPB = 4;             // waves per block (256 threads)

// Pass 1: one pass over enc_out. Each wave owns a contiguous run of rows of
// one batch. For each row: coalesced float4 loads (kept in registers), dot
// with dec_h fragment, wave-reduce, online-softmax accumulate into registers.
// Writes raw scaled scores to the weights section of d_out, and per-wave
// partials (m, l, acc[H]) to workspace.
__global__ __launch_bounds__(256) void attn_pass1(
    const float* __restrict__ dec_h, const float* __restrict__ enc,
    float* __restrict__ scores, float* __restrict__ acc_ws,
    float* __restrict__ ml_ws, int chunks, int rows_per_wave) {
  const int b = blockIdx.y;
  const int chunk = blockIdx.x;
  const int wave = threadIdx.x >> 6;
  const int lane = threadIdx.x & 63;
  const int wslot = chunk * WPB + wave;          // [0, chunks*WPB)
  const int t0 = wslot * rows_per_wave;

  // dec fragment: this lane's 16 h-positions (4 strided float4 groups)
  const float* decb = dec_h + (size_t)b * H + lane * 4;
  const float4 d0 = *(const float4*)(decb + 0 * 256);
  const float4 d1 = *(const float4*)(decb + 1 * 256);
  const float4 d2 = *(const float4*)(decb + 2 * 256);
  const float4 d3 = *(const float4*)(decb + 3 * 256);

  float4 a0 = {0.f, 0.f, 0.f, 0.f}, a1 = {0.f, 0.f, 0.f, 0.f};
  float4 a2 = {0.f, 0.f, 0.f, 0.f}, a3 = {0.f, 0.f, 0.f, 0.f};
  float m = -INFINITY;
  float l = 0.f;

  const float* row = enc + ((size_t)b * T + t0) * H + lane * 4;
  float* srow = scores + (size_t)b * T + t0;

#pragma unroll 2
  for (int r = 0; r < rows_per_wave; ++r) {
    const float4 x0 = *(const float4*)(row + 0 * 256);
    const float4 x1 = *(const float4*)(row + 1 * 256);
    const float4 x2 = *(const float4*)(row + 2 * 256);
    const float4 x3 = *(const float4*)(row + 3 * 256);
    row += H;

    float s;
    s  = x0.x * d0.x + x0.y * d0.y + x0.z * d0.z + x0.w * d0.w;
    s += x1.x * d1.x + x1.y * d1.y + x1.z * d1.z + x1.w * d1.w;
    s += x2.x * d2.x + x2.y * d2.y + x2.z * d2.z + x2.w * d2.w;
    s += x3.x * d3.x + x3.y * d3.y + x3.z * d3.z + x3.w * d3.w;
#pragma unroll
    for (int off = 32; off > 0; off >>= 1) s += __shfl_xor(s, off, 64);
    s *= SCALE;

    if (lane == 0) srow[r] = s;

    // online softmax (s is wave-uniform -> branch is non-divergent)
    if (s > m) {
      const float sc = __expf(m - s);  // m==-inf first time -> 0
      a0.x *= sc; a0.y *= sc; a0.z *= sc; a0.w *= sc;
      a1.x *= sc; a1.y *= sc; a1.z *= sc; a1.w *= sc;
      a2.x *= sc; a2.y *= sc; a2.z *= sc; a2.w *= sc;
      a3.x *= sc; a3.y *= sc; a3.z *= sc; a3.w *= sc;
      l *= sc;
      m = s;
    }
    const float p = __expf(s - m);
    l += p;
    a0.x += p * x0.x; a0.y += p * x0.y; a0.z += p * x0.z; a0.w += p * x0.w;
    a1.x += p * x1.x; a1.y += p * x1.y; a1.z += p * x1.z; a1.w += p * x1.w;
    a2.x += p * x2.x; a2.y += p * x2.y; a2.z += p * x2.z; a2.w += p * x2.w;
    a3.x += p * x3.x; a3.y += p * x3.y; a3.z += p * x3.z; a3.w += p * x3.w;
  }

  const size_t pi = (size_t)b * chunks * WPB + wslot;
  float* aw = acc_ws + pi * H + lane * 4;
  *(float4*)(aw + 0 * 256) = a0;
  *(float4*)(aw + 1 * 256) = a1;
  *(float4*)(aw + 2 * 256) = a2;
  *(float4*)(aw + 3 * 256) = a3;
  if (lane == 0) {
    ml_ws[2 * pi]     = m;
    ml_ws[2 * pi + 1] = l;
  }
}

// Pass 2: per batch, combine np partials -> ctx; normalize weights in place.
__global__ __launch_bounds__(256) void attn_pass2(
    const float* __restrict__ acc_ws, const float* __restrict__ ml_ws,
    float* __restrict__ ctx, float* __restrict__ weights, int np) {
  const int b = blockIdx.x;
  const int tid = threadIdx.x;
  const float* ml = ml_ws + 2 * (size_t)b * np;

  float M = -INFINITY;
  for (int i = 0; i < np; ++i) M = fmaxf(M, ml[2 * i]);
  float L = 0.f;
  for (int i = 0; i < np; ++i) L += ml[2 * i + 1] * __expf(ml[2 * i] - M);
  const float invL = 1.f / L;

  // ctx: 256 threads x 4 floats = 1024
  float4 a = {0.f, 0.f, 0.f, 0.f};
  const float* aw = acc_ws + (size_t)b * np * H + tid * 4;
  for (int i = 0; i < np; ++i) {
    const float w = __expf(ml[2 * i] - M);
    const float4 v = *(const float4*)(aw + (size_t)i * H);
    a.x += w * v.x; a.y += w * v.y; a.z += w * v.z; a.w += w * v.w;
  }
  a.x *= invL; a.y *= invL; a.z *= invL; a.w *= invL;
  *(float4*)(ctx + (size_t)b * H + tid * 4) = a;

  float* wrow = weights + (size_t)b * T;
  for (int t = tid; t < T; t += 256) {
    wrow[t] = __expf(wrow[t] - M) * invL;
  }
}

}  // namespace

extern "C" void kernel_launch(void* const* d_in, const int* in_sizes, int n_in,
                              void* d_out, int out_size, void* d_ws,
                              size_t ws_size, hipStream_t stream) {
  const float* dec_h = (const float*)d_in[0];
  const float* enc   = (const float*)d_in[1];
  float* ctx     = (float*)d_out;            // [B,H]
  float* weights = (float*)d_out + (size_t)B * H;  // [B,T]

  // Pick the largest chunk count whose partial workspace fits in d_ws.
  // need = B*chunks*WPB*(H+2)*4 bytes ~= chunks * 1.003 MB
  int chunks = 16;
  while (chunks > 1 &&
         (size_t)B * chunks * WPB * (H + 2) * sizeof(float) > ws_size)
    chunks >>= 1;
  const int rows_per_wave = T / (chunks * WPB);
  const int np = chunks * WPB;

  float* acc_ws = (float*)d_ws;                          // [B*np][H]
  float* ml_ws  = acc_ws + (size_t)B * np * H;           // [B*np][2]

  dim3 g1(chunks, B);
  attn_pass1<<<g1, 256, 0, stream>>>(dec_h, enc, weights, acc_ws, ml_ws,
                                     chunks, rows_per_wave);
  attn_pass2<<<B, 256, 0, stream>>>(acc_ws, ml_ws, ctx, weights, np);
}

// Round 3
// 208.432 us; speedup vs baseline: 1.1048x; 1.1048x over previous
//
#include <hip/hip_runtime.h>
#include <math.h>

namespace {

constexpr int B = 64;
constexpr int T = 4096;
constexpr int H = 1024;
constexpr float SCALE = 0.03125f;  // 1/sqrt(1024)
constexpr int WPB = 4;             // waves per block (256 threads)

typedef float v4f __attribute__((ext_vector_type(4)));

// Pass 1: single pass over enc_out with online softmax.
// Each wave owns rpw contiguous rows of one batch. Depth-1 software
// pipeline: row r+1's loads are issued before row r's reduce chain so the
// wave always has ~4KB in flight. Scores are banked per-lane and stored
// coalesced once per 64 rows.
__global__ __launch_bounds__(256) void attn_pass1(
    const float* __restrict__ dec_h, const float* __restrict__ enc,
    float* __restrict__ scores, float* __restrict__ acc_ws,
    float* __restrict__ ml_ws, int chunks, int rpw) {
  const int b = blockIdx.y;
  const int wave = threadIdx.x >> 6;
  const int lane = threadIdx.x & 63;
  const int wslot = blockIdx.x * WPB + wave;  // [0, chunks*WPB)
  const int t0 = wslot * rpw;

  // dec fragment: this lane's 16 h-positions (4 strided groups of 4)
  const float* decb = dec_h + (size_t)b * H + lane * 4;
  const v4f d0 = *(const v4f*)(decb);
  const v4f d1 = *(const v4f*)(decb + 256);
  const v4f d2 = *(const v4f*)(decb + 512);
  const v4f d3 = *(const v4f*)(decb + 768);

  v4f a0 = {0.f, 0.f, 0.f, 0.f}, a1 = {0.f, 0.f, 0.f, 0.f};
  v4f a2 = {0.f, 0.f, 0.f, 0.f}, a3 = {0.f, 0.f, 0.f, 0.f};
  float m = -INFINITY;
  float l = 0.f;
  float sv = 0.f;

  // row pointer in v4f units; lane's slice at lane + k*64
  const v4f* rp = (const v4f*)(enc + ((size_t)b * T + t0) * H) + lane;
  float* srow = scores + (size_t)b * T + t0;

  v4f x0 = __builtin_nontemporal_load(rp);
  v4f x1 = __builtin_nontemporal_load(rp + 64);
  v4f x2 = __builtin_nontemporal_load(rp + 128);
  v4f x3 = __builtin_nontemporal_load(rp + 192);

  for (int r = 0; r < rpw; ++r) {
    v4f y0, y1, y2, y3;
    if (r + 1 < rpw) {
      const v4f* rq = rp + 256;
      y0 = __builtin_nontemporal_load(rq);
      y1 = __builtin_nontemporal_load(rq + 64);
      y2 = __builtin_nontemporal_load(rq + 128);
      y3 = __builtin_nontemporal_load(rq + 192);
    }
    rp += 256;

    // dot (two chains of fmas)
    float sA = x0[0] * d0[0] + x0[1] * d0[1] + x0[2] * d0[2] + x0[3] * d0[3];
    float sB = x1[0] * d1[0] + x1[1] * d1[1] + x1[2] * d1[2] + x1[3] * d1[3];
    sA += x2[0] * d2[0] + x2[1] * d2[1] + x2[2] * d2[2] + x2[3] * d2[3];
    sB += x3[0] * d3[0] + x3[1] * d3[1] + x3[2] * d3[2] + x3[3] * d3[3];
    float s = sA + sB;
#pragma unroll
    for (int off = 32; off > 0; off >>= 1) s += __shfl_xor(s, off, 64);
    s *= SCALE;

    // bank the wave-uniform score; one coalesced store per 64 rows
    sv = (lane == (r & 63)) ? s : sv;
    if ((r & 63) == 63) srow[(r & ~63) + lane] = sv;

    // online softmax (s is wave-uniform -> branch is non-divergent)
    if (s > m) {
      const float sc = __expf(m - s);  // m==-inf first time -> 0
      a0 *= sc; a1 *= sc; a2 *= sc; a3 *= sc;
      l *= sc;
      m = s;
    }
    const float p = __expf(s - m);
    l += p;
    a0 += p * x0;
    a1 += p * x1;
    a2 += p * x2;
    a3 += p * x3;

    x0 = y0; x1 = y1; x2 = y2; x3 = y3;
  }

  const size_t pi = (size_t)b * chunks * WPB + wslot;
  float* aw = acc_ws + pi * H + lane * 4;
  *(v4f*)(aw)       = a0;
  *(v4f*)(aw + 256) = a1;
  *(v4f*)(aw + 512) = a2;
  *(v4f*)(aw + 768) = a3;
  if (lane == 0) {
    ml_ws[2 * pi]     = m;
    ml_ws[2 * pi + 1] = l;
  }
}

// Pass 2: per batch, combine np partials -> ctx; normalize weights in place.
__global__ __launch_bounds__(256) void attn_pass2(
    const float* __restrict__ acc_ws, const float* __restrict__ ml_ws,
    float* __restrict__ ctx, float* __restrict__ weights, int np) {
  const int b = blockIdx.x;
  const int tid = threadIdx.x;
  const float* ml = ml_ws + 2 * (size_t)b * np;

  float M = -INFINITY;
  for (int i = 0; i < np; ++i) M = fmaxf(M, ml[2 * i]);
  float L = 0.f;
  for (int i = 0; i < np; ++i) L += ml[2 * i + 1] * __expf(ml[2 * i] - M);
  const float invL = 1.f / L;

  // ctx: 256 threads x 4 floats = 1024
  v4f a = {0.f, 0.f, 0.f, 0.f};
  const float* aw = acc_ws + (size_t)b * np * H + tid * 4;
  for (int i = 0; i < np; ++i) {
    const float w = __expf(ml[2 * i] - M);
    const v4f v = *(const v4f*)(aw + (size_t)i * H);
    a += w * v;
  }
  a *= invL;
  *(v4f*)(ctx + (size_t)b * H + tid * 4) = a;

  float* wrow = weights + (size_t)b * T;
  for (int t = tid; t < T; t += 256) {
    wrow[t] = __expf(wrow[t] - M) * invL;
  }
}

}  // namespace

extern "C" void kernel_launch(void* const* d_in, const int* in_sizes, int n_in,
                              void* d_out, int out_size, void* d_ws,
                              size_t ws_size, hipStream_t stream) {
  const float* dec_h = (const float*)d_in[0];
  const float* enc   = (const float*)d_in[1];
  float* ctx     = (float*)d_out;                  // [B,H]
  float* weights = (float*)d_out + (size_t)B * H;  // [B,T]

  // Largest chunk count whose partial workspace fits in d_ws.
  // need = B*chunks*WPB*(H+2)*4 bytes ~= chunks * 1.05 MB
  int chunks = 16;
  while (chunks > 1 &&
         (size_t)B * chunks * WPB * (H + 2) * sizeof(float) > ws_size)
    chunks >>= 1;
  const int rpw = T / (chunks * WPB);  // 64 at chunks=16 (multiple of 64)
  const int np = chunks * WPB;

  float* acc_ws = (float*)d_ws;                 // [B*np][H]
  float* ml_ws  = acc_ws + (size_t)B * np * H;  // [B*np][2]

  dim3 g1(chunks, B);
  attn_pass1<<<g1, 256, 0, stream>>>(dec_h, enc, weights, acc_ws, ml_ws,
                                     chunks, rpw);
  attn_pass2<<<B, 256, 0, stream>>>(acc_ws, ml_ws, ctx, weights, np);
}